// Round 5
// baseline (1739.372 us; speedup 1.0000x reference)
//
#include <hip/hip_runtime.h>

#define B_ 32
#define NP 196
#define PD 768
#define DM 512
#define NC 1000
#define MAT (NP*NP)

// ---------------- patchify + LN + pos ----------------
__global__ __launch_bounds__(256) void k_patchify(
    const float* __restrict__ img, const float* __restrict__ g,
    const float* __restrict__ be, const float* __restrict__ pos,
    float* __restrict__ x) {
  int bn = blockIdx.x;
  int b = bn / NP, n = bn % NP;
  int gh = n / 14, gw = n % 14;
  int t = threadIdx.x;
  float vals[3]; float s = 0.f, ss = 0.f;
  #pragma unroll
  for (int k = 0; k < 3; ++k) {
    int e = t + (k << 8);
    int inner = e & 255;
    int ph = inner >> 4, pw = inner & 15;
    float v = img[((b*3 + k)*224 + gh*16 + ph)*224 + gw*16 + pw];
    vals[k] = v; s += v; ss += v*v;
  }
  __shared__ float rb[8];
  for (int o = 32; o; o >>= 1) { s += __shfl_down(s,o); ss += __shfl_down(ss,o); }
  if ((t & 63) == 0) { rb[t>>6] = s; rb[4+(t>>6)] = ss; }
  __syncthreads();
  float S = rb[0]+rb[1]+rb[2]+rb[3], SS = rb[4]+rb[5]+rb[6]+rb[7];
  float mu = S * (1.f/768.f);
  float var = SS * (1.f/768.f) - mu*mu;
  float inv = rsqrtf(var + 1e-5f);
  #pragma unroll
  for (int k = 0; k < 3; ++k) {
    int e = t + (k << 8);
    x[(size_t)bn*PD + e] = (vals[k]-mu)*inv*g[e] + be[e] + pos[n*PD + e];
  }
}

// ---------------- merged Q/V GEMM: M=6272 K=768 N=512 (64x64 tile) ----------------
__global__ __launch_bounds__(256) void k_qv(
    const float* __restrict__ A,
    const float* __restrict__ wq, const float* __restrict__ bq,
    const float* __restrict__ wv, const float* __restrict__ bv,
    float* __restrict__ qo, float* __restrict__ vo) {
  const float* W    = blockIdx.z ? wv : wq;
  const float* bias = blockIdx.z ? bv : bq;
  float* out        = blockIdx.z ? vo : qo;
  __shared__ __align__(16) float As[16][68];
  __shared__ __align__(16) float Bs[16][64];
  int n0 = blockIdx.x * 64, m0 = blockIdx.y * 64;
  int t = threadIdx.x, tx = t & 15, ty = t >> 4;
  int alr = t >> 2, alc = (t & 3) << 2;
  int blr = t >> 4, blc = (t & 15) << 2;
  float acc[4][4] = {};
  for (int k0 = 0; k0 < 768; k0 += 16) {
    float4 av = *reinterpret_cast<const float4*>(&A[(size_t)(m0+alr)*768 + k0 + alc]);
    float4 bvv = *reinterpret_cast<const float4*>(&W[(size_t)(k0+blr)*512 + n0 + blc]);
    As[alc+0][alr] = av.x; As[alc+1][alr] = av.y;
    As[alc+2][alr] = av.z; As[alc+3][alr] = av.w;
    *reinterpret_cast<float4*>(&Bs[blr][blc]) = bvv;
    __syncthreads();
    #pragma unroll
    for (int kt = 0; kt < 16; ++kt) {
      float a4[4], b4[4];
      *reinterpret_cast<float4*>(a4) = *reinterpret_cast<const float4*>(&As[kt][ty<<2]);
      *reinterpret_cast<float4*>(b4) = *reinterpret_cast<const float4*>(&Bs[kt][tx<<2]);
      #pragma unroll
      for (int i = 0; i < 4; ++i)
        #pragma unroll
        for (int j = 0; j < 4; ++j) acc[i][j] += a4[i]*b4[j];
    }
    __syncthreads();
  }
  float4 bb = *reinterpret_cast<const float4*>(&bias[n0 + (tx<<2)]);
  float bb4[4] = {bb.x, bb.y, bb.z, bb.w};
  #pragma unroll
  for (int i = 0; i < 4; ++i) {
    float4 o;
    o.x = acc[i][0]+bb4[0]; o.y = acc[i][1]+bb4[1];
    o.z = acc[i][2]+bb4[2]; o.w = acc[i][3]+bb4[3];
    *reinterpret_cast<float4*>(&out[(size_t)(m0+(ty<<2)+i)*512 + n0 + (tx<<2)]) = o;
  }
}

// ---------------- merged row LayerNorm for q (scale 1) and v (scale 1/196) ----------------
__global__ __launch_bounds__(256) void k_ln2(
    float* __restrict__ q, float* __restrict__ v,
    const float* __restrict__ gq, const float* __restrict__ bq,
    const float* __restrict__ gv, const float* __restrict__ bv) {
  int r = blockIdx.x; bool hv = (r >= B_*NP); if (hv) r -= B_*NP;
  float* X = hv ? v : q;
  const float* g  = hv ? gv : gq;
  const float* be = hv ? bv : bq;
  float scale = hv ? (1.f/196.f) : 1.f;
  int t = threadIdx.x;
  float v0 = X[(size_t)r*512 + t], v1 = X[(size_t)r*512 + 256 + t];
  float s = v0+v1, ss = v0*v0+v1*v1;
  __shared__ float rb[8];
  for (int o = 32; o; o >>= 1) { s += __shfl_down(s,o); ss += __shfl_down(ss,o); }
  if ((t&63)==0) { rb[t>>6]=s; rb[4+(t>>6)]=ss; }
  __syncthreads();
  float S = rb[0]+rb[1]+rb[2]+rb[3], SS = rb[4]+rb[5]+rb[6]+rb[7];
  float mu = S*(1.f/512.f), var = SS*(1.f/512.f)-mu*mu;
  float inv = rsqrtf(var+1e-5f);
  X[(size_t)r*512+t]     = ((v0-mu)*inv*g[t]+be[t])*scale;
  X[(size_t)r*512+256+t] = ((v1-mu)*inv*g[t+256]+be[t+256])*scale;
}

// ---------------- merged Gram: z<32: A=2VV^T+I ; z>=32: p=-2QV^T+1/196 ----------------
__global__ __launch_bounds__(256) void k_gram(
    const float* __restrict__ q, const float* __restrict__ v,
    float* __restrict__ Ao, float* __restrict__ po) {
  int zz = blockIdx.z; int b = zz & 31; bool hp = (zz >= 32);
  float alpha  = hp ? -2.f : 2.f;
  float diagAdd = hp ? 0.f : 1.f;
  float cAdd   = hp ? (1.f/196.f) : 0.f;
  const float* Xb = (hp ? q : v) + (size_t)b*NP*512;
  const float* Yb = v + (size_t)b*NP*512;
  float* out = (hp ? po : Ao) + (size_t)b*MAT;
  int c0 = blockIdx.x * 64, r0 = blockIdx.y * 64;
  __shared__ __align__(16) float Xs[16][68];
  __shared__ __align__(16) float Ys[16][68];
  int t = threadIdx.x, tx = t & 15, ty = t >> 4;
  int lr = t >> 2, lc4 = (t & 3) << 2;
  float acc[4][4] = {};
  int xr = min(r0 + lr, NP-1), yr = min(c0 + lr, NP-1);
  for (int k0 = 0; k0 < 512; k0 += 16) {
    float4 xv = *reinterpret_cast<const float4*>(&Xb[(size_t)xr*512 + k0 + lc4]);
    float4 yv = *reinterpret_cast<const float4*>(&Yb[(size_t)yr*512 + k0 + lc4]);
    Xs[lc4+0][lr] = xv.x; Xs[lc4+1][lr] = xv.y;
    Xs[lc4+2][lr] = xv.z; Xs[lc4+3][lr] = xv.w;
    Ys[lc4+0][lr] = yv.x; Ys[lc4+1][lr] = yv.y;
    Ys[lc4+2][lr] = yv.z; Ys[lc4+3][lr] = yv.w;
    __syncthreads();
    #pragma unroll
    for (int kt = 0; kt < 16; ++kt) {
      float a4[4], b4[4];
      *reinterpret_cast<float4*>(a4) = *reinterpret_cast<const float4*>(&Xs[kt][ty<<2]);
      *reinterpret_cast<float4*>(b4) = *reinterpret_cast<const float4*>(&Ys[kt][tx<<2]);
      #pragma unroll
      for (int i = 0; i < 4; ++i)
        #pragma unroll
        for (int j = 0; j < 4; ++j) acc[i][j] += a4[i]*b4[j];
    }
    __syncthreads();
  }
  #pragma unroll
  for (int i = 0; i < 4; ++i) {
    int r = r0 + (ty<<2) + i; if (r >= NP) continue;
    #pragma unroll
    for (int j = 0; j < 4; ++j) {
      int c = c0 + (tx<<2) + j; if (c >= NP) continue;
      out[(size_t)r*NP + c] = alpha*acc[i][j] + cAdd + (r==c ? diagAdd : 0.f);
    }
  }
}

// ---------------- NS init: ninf bound, X0 = c*I, Y0 = c*A (Y tracks A@X) ----------------
__global__ __launch_bounds__(256) void k_nsinit2(
    const float* __restrict__ A, float* __restrict__ X, float* __restrict__ Y) {
  int b = blockIdx.x, t = threadIdx.x;
  const float* Ab = A + (size_t)b*MAT;
  __shared__ float sm[256];
  float lm = 0.f;
  if (t < NP) {
    float s = 0.f;
    for (int j = 0; j < NP; ++j) {
      float v = Ab[t*NP + j];
      if (j == t) v -= 1.f;
      s += fabsf(v);
    }
    lm = s;
  }
  sm[t] = lm; __syncthreads();
  for (int o = 128; o; o >>= 1) { if (t < o) sm[t] = fmaxf(sm[t], sm[t+o]); __syncthreads(); }
  float cc = 2.f / (2.f + sm[0]);
  float* Xb = X + (size_t)b*MAT;
  float* Yb = Y + (size_t)b*MAT;
  for (int idx = t; idx < MAT; idx += 256) {
    Xb[idx] = (idx % (NP+1) == 0) ? cc : 0.f;
    Yb[idx] = cc * Ab[idx];
  }
}

// ---------------- NS iter (X,Y independent halves): z<32: Xn=2X-X@Y ; z>=32: Yn=2Y-Y@Y ----------------
__global__ __launch_bounds__(256) void k_ns(
    const float* __restrict__ X, const float* __restrict__ Y,
    float* __restrict__ Xn, float* __restrict__ Yn) {
  int zz = blockIdx.z; int b = zz & 31; bool hy = (zz >= 32);
  const float* Lb = (hy ? Y : X) + (size_t)b*MAT;
  const float* Rb = Y + (size_t)b*MAT;
  float* Ob = (hy ? Yn : Xn) + (size_t)b*MAT;
  int c0 = blockIdx.x * 64, r0 = blockIdx.y * 64;
  __shared__ __align__(16) float Ls[16][68];
  __shared__ __align__(16) float Rs[16][64];
  int t = threadIdx.x, tx = t & 15, ty = t >> 4;
  int alr = t >> 2, alc = (t & 3) << 2;
  int blr = t >> 4, blc = (t & 15) << 2;
  float acc[4][4] = {};
  int lrow = min(r0 + alr, NP-1);
  for (int k0 = 0; k0 < NP; k0 += 16) {
    float4 lv = {0.f,0.f,0.f,0.f};
    if (k0 + alc < NP) lv = *reinterpret_cast<const float4*>(&Lb[(size_t)lrow*NP + k0 + alc]);
    float4 rv = {0.f,0.f,0.f,0.f};
    if (k0 + blr < NP) rv = *reinterpret_cast<const float4*>(&Rb[(size_t)(k0+blr)*NP + c0 + blc]);
    Ls[alc+0][alr] = lv.x; Ls[alc+1][alr] = lv.y;
    Ls[alc+2][alr] = lv.z; Ls[alc+3][alr] = lv.w;
    *reinterpret_cast<float4*>(&Rs[blr][blc]) = rv;
    __syncthreads();
    #pragma unroll
    for (int kt = 0; kt < 16; ++kt) {
      float a4[4], b4[4];
      *reinterpret_cast<float4*>(a4) = *reinterpret_cast<const float4*>(&Ls[kt][ty<<2]);
      *reinterpret_cast<float4*>(b4) = *reinterpret_cast<const float4*>(&Rs[kt][tx<<2]);
      #pragma unroll
      for (int i = 0; i < 4; ++i)
        #pragma unroll
        for (int j = 0; j < 4; ++j) acc[i][j] += a4[i]*b4[j];
    }
    __syncthreads();
  }
  #pragma unroll
  for (int i = 0; i < 4; ++i) {
    int r = r0 + (ty<<2) + i; if (r >= NP) continue;
    #pragma unroll
    for (int j = 0; j < 4; ++j) {
      int c = c0 + (tx<<2) + j; if (c >= NP) continue;
      Ob[(size_t)r*NP + c] = 2.f*Lb[(size_t)r*NP + c] - acc[i][j];
    }
  }
}

// ---------------- fused 50-iter ADMM v5 ----------------
// 800 blocks (25 tiles x 8 tokens x 32 batches), 256 thr, 4 blocks/CU (one
// generation: launch_bounds(256,4); LDS 37.8 KB; VGPR<=128).
// Lane tx<28 owns m in {tx+28k} (coalesced Minv loads). j-split balanced:
// ty<4: 25 rows (6 quads + 1 epilogue row, waves 0/1 uniform), ty>=4: 24.
// Reduction: shfl_xor(32) then 28 ds_write_b64 into rp[4][7][28][10]
// (lane stride 10 -> 2-way bank alias = free). Minv from L2 (b=bid&31 pins
// 4 batches/XCD).
__global__ __launch_bounds__(256, 4) void k_admm5(
    const float* __restrict__ Minv, const float* __restrict__ P,
    float* __restrict__ w) {
  int bid = blockIdx.x;
  int b = bid & 31;
  int tile = bid >> 5;
  int n0 = tile * 8;
  int t = threadIdx.x;
  int tx = t & 31, ty = t >> 5, wv = t >> 6;
  bool act = (tx < 28);
  int m0 = tx;

  __shared__ __align__(16) float rsT[8][200];       // rhs, [token][m]
  __shared__ __align__(16) float rp[4][7][28][10];  // [wave][k][tx][n(8)+pad2]

  const float* Mb = Minv + (size_t)b * MAT;
  const float* Pb = P + (size_t)b * MAT;

  int jstart = (ty < 4) ? 25 * ty : 100 + 24 * (ty - 4);

  float z[7], u[7], pr[7];
  #pragma unroll
  for (int k = 0; k < 7; ++k) { z[k] = 0.f; u[k] = 0.f; pr[k] = 0.f; }

  int ng = min(n0 + ty, NP - 1);   // pad dups token 195 (masked later)
  if (act) {
    const float* prow = Pb + (size_t)ng * NP + m0;
    #pragma unroll
    for (int k = 0; k < 7; ++k) pr[k] = prow[28*k];
    #pragma unroll
    for (int k = 0; k < 7; ++k) rsT[ty][m0 + 28*k] = -pr[k];  // rhs0 = -p
  }
  __syncthreads();

  for (int it = 0; it < 50; ++it) {
    float acc[8][7];
    if (act) {
      #pragma unroll
      for (int n = 0; n < 8; ++n)
        #pragma unroll
        for (int k = 0; k < 7; ++k) acc[n][k] = 0.f;
      const float* mrow = Mb + (size_t)jstart * NP + m0;
      #pragma unroll 2
      for (int q = 0; q < 6; ++q) {
        int j = jstart + (q << 2);
        float mv[4][7];
        {
          const float* mr = mrow;
          #pragma unroll
          for (int jj = 0; jj < 4; ++jj) {
            #pragma unroll
            for (int k = 0; k < 7; ++k) mv[jj][k] = mr[28*k];
            mr += NP;
          }
        }
        float4 rr[8];
        #pragma unroll
        for (int n = 0; n < 8; ++n)
          rr[n] = *reinterpret_cast<const float4*>(&rsT[n][j]);
        #pragma unroll
        for (int jj = 0; jj < 4; ++jj)
          #pragma unroll
          for (int n = 0; n < 8; ++n) {
            float rv = (jj == 0) ? rr[n].x : (jj == 1) ? rr[n].y
                     : (jj == 2) ? rr[n].z : rr[n].w;
            #pragma unroll
            for (int k = 0; k < 7; ++k)
              acc[n][k] = fmaf(mv[jj][k], rv, acc[n][k]);
          }
        mrow += 4 * NP;
      }
      // epilogue row for ty<4 (waves 0,1: uniform)
      if (ty < 4) {
        int j = jstart + 24;
        const float* mr = Mb + (size_t)j * NP + m0;
        float mv1[7];
        #pragma unroll
        for (int k = 0; k < 7; ++k) mv1[k] = mr[28*k];
        #pragma unroll
        for (int n = 0; n < 8; ++n) {
          float rv = rsT[n][j];
          #pragma unroll
          for (int k = 0; k < 7; ++k)
            acc[n][k] = fmaf(mv1[k], rv, acc[n][k]);
        }
      }
      // combine the two half-wave j-ranges (result valid in both halves)
      #pragma unroll
      for (int n = 0; n < 8; ++n)
        #pragma unroll
        for (int k = 0; k < 7; ++k)
          acc[n][k] += __shfl_xor(acc[n][k], 32, 64);
      if ((t & 63) < 32) {
        #pragma unroll
        for (int k = 0; k < 7; ++k)
          #pragma unroll
          for (int n2 = 0; n2 < 4; ++n2) {
            float2 v2; v2.x = acc[2*n2][k]; v2.y = acc[2*n2+1][k];
            *reinterpret_cast<float2*>(&rp[wv][k][tx][2*n2]) = v2;
          }
      }
    }
    __syncthreads();
    if (act) {
      #pragma unroll
      for (int k = 0; k < 7; ++k) {
        int m = m0 + 28*k;
        float x = rp[0][k][tx][ty] + rp[1][k][tx][ty]
                + rp[2][k][tx][ty] + rp[3][k][tx][ty];
        float xpu = x + u[k];
        float zz = fminf(fmaxf(xpu, 0.f), 1.f);
        u[k] = xpu - zz;
        z[k] = zz;
        rsT[ty][m] = zz - u[k] - pr[k];
      }
    }
    __syncthreads();
  }

  // coeffs = z / (sum z + 1e-10); w[b][m] += mean_n coeffs  (z>=0 after clip)
  float s = 0.f;
  #pragma unroll
  for (int k = 0; k < 7; ++k) s += z[k];
  #pragma unroll
  for (int o = 16; o; o >>= 1) s += __shfl_xor(s, o, 64);
  float inv = 1.f / (s + 1e-10f);
  if (n0 + ty >= NP) inv = 0.f;   // mask pad tokens
  if (act) {
    #pragma unroll
    for (int k = 0; k < 7; ++k)
      atomicAdd(&w[b*NP + m0 + 28*k], z[k] * inv * (1.f/196.f));
  }
}

// ---------------- fused pooled + LN + head + softmax ----------------
__global__ __launch_bounds__(256) void k_finish(
    const float* __restrict__ w, const float* __restrict__ V,
    const float* __restrict__ g, const float* __restrict__ be,
    const float* __restrict__ Wm, const float* __restrict__ bm,
    float* __restrict__ out) {
  int b = blockIdx.x, t = threadIdx.x;
  __shared__ float ws_[NP];
  __shared__ float pl[512];
  __shared__ float rb[8];
  if (t < NP) ws_[t] = w[b*NP + t];
  __syncthreads();
  const float* Vb = V + (size_t)b*NP*512;
  float a0 = 0.f, a1 = 0.f;
  #pragma unroll 4
  for (int m = 0; m < NP; ++m) {
    float wm = ws_[m];
    a0 = fmaf(wm, Vb[(size_t)m*512 + t], a0);
    a1 = fmaf(wm, Vb[(size_t)m*512 + 256 + t], a1);
  }
  float s = a0+a1, ss = a0*a0+a1*a1;
  for (int o = 32; o; o >>= 1) { s += __shfl_down(s,o); ss += __shfl_down(ss,o); }
  if ((t&63)==0) { rb[t>>6]=s; rb[4+(t>>6)]=ss; }
  __syncthreads();
  float S = rb[0]+rb[1]+rb[2]+rb[3], SS = rb[4]+rb[5]+rb[6]+rb[7];
  float mu = S*(1.f/512.f), var = SS*(1.f/512.f)-mu*mu, inv = rsqrtf(var+1e-5f);
  pl[t]     = (a0-mu)*inv*g[t] + be[t];
  pl[t+256] = (a1-mu)*inv*g[t+256] + be[t+256];
  __syncthreads();
  float lg[4];
  #pragma unroll
  for (int qq = 0; qq < 4; ++qq) {
    int c = t + (qq<<8);
    float a = -1e30f;
    if (c < NC) {
      a = bm[c];
      #pragma unroll 8
      for (int k = 0; k < 512; ++k) a += pl[k]*Wm[(size_t)k*NC + c];
    }
    lg[qq] = a;
  }
  float mx = fmaxf(fmaxf(lg[0],lg[1]), fmaxf(lg[2],lg[3]));
  for (int o = 32; o; o >>= 1) mx = fmaxf(mx, __shfl_down(mx,o));
  __syncthreads();
  if ((t&63)==0) rb[t>>6] = mx;
  __syncthreads();
  float MX = fmaxf(fmaxf(rb[0],rb[1]), fmaxf(rb[2],rb[3]));
  float es = 0.f, ev[4];
  #pragma unroll
  for (int qq = 0; qq < 4; ++qq) {
    int c = t + (qq<<8);
    ev[qq] = (c < NC) ? __expf(lg[qq]-MX) : 0.f;
    es += ev[qq];
  }
  for (int o = 32; o; o >>= 1) es += __shfl_down(es,o);
  __syncthreads();
  if ((t&63)==0) rb[4+(t>>6)] = es;
  __syncthreads();
  float SUM = rb[4]+rb[5]+rb[6]+rb[7];
  float rinv = 1.f/SUM;
  #pragma unroll
  for (int qq = 0; qq < 4; ++qq) {
    int c = t + (qq<<8);
    if (c < NC) out[(size_t)b*NC + c] = ev[qq]*rinv;
  }
}

extern "C" void kernel_launch(void* const* d_in, const int* in_sizes, int n_in,
                              void* d_out, int out_size, void* d_ws, size_t ws_size,
                              hipStream_t stream) {
  const float* img = (const float*)d_in[0];
  const float* lpg = (const float*)d_in[1];
  const float* lpb = (const float*)d_in[2];
  const float* wqw = (const float*)d_in[3];
  const float* wqb = (const float*)d_in[4];
  const float* lqg = (const float*)d_in[5];
  const float* lqb = (const float*)d_in[6];
  const float* wvw = (const float*)d_in[7];
  const float* wvb = (const float*)d_in[8];
  const float* lvg = (const float*)d_in[9];
  const float* lvb = (const float*)d_in[10];
  const float* pos = (const float*)d_in[11];
  const float* mlg = (const float*)d_in[12];
  const float* mlb = (const float*)d_in[13];
  const float* mw  = (const float*)d_in[14];
  const float* mb  = (const float*)d_in[15];
  float* outp = (float*)d_out;

  float* ws = (float*)d_ws;
  size_t off = 0;
  float* x  = ws + off;      off += (size_t)B_*NP*PD;
  float* q  = ws + off;      off += (size_t)B_*NP*DM;
  float* v  = ws + off;      off += (size_t)B_*NP*DM;
  size_t matp = (size_t)B_*MAT + 256;  // +tail pad for benign overrun reads
  float* A  = ws + off;      off += matp;   // doubles as Yb after nsinit consumes it
  float* p  = ws + off;      off += matp;
  float* Xa = ws + off;      off += matp;
  float* Xb = ws + off;      off += matp;
  float* Ya = ws + off;      off += matp;
  float* Yb = A;                            // alias: A dead after k_nsinit2
  float* w  = ws + off;      off += (size_t)B_*NP;
  if (ws_size < off * sizeof(float)) return;  // workspace too small -> fail loudly

  k_patchify<<<dim3(B_*NP), 256, 0, stream>>>(img, lpg, lpb, pos, x);
  k_qv<<<dim3(8, 98, 2), 256, 0, stream>>>(x, wqw, wqb, wvw, wvb, q, v);
  k_ln2<<<dim3(2*B_*NP), 256, 0, stream>>>(q, v, lqg, lqb, lvg, lvb);
  // A = 2VV^T + I ; p = -2QV^T + 1/196   (one dispatch)
  k_gram<<<dim3(4,4,64), 256, 0, stream>>>(q, v, A, p);
  // Newton-Schulz with Y=A@X invariant: X<-2X-XY, Y<-2Y-YY (independent).
  // 3 iters: rho0^8 ~ 5e-9 at measured ninf~0.2.
  k_nsinit2<<<dim3(B_), 256, 0, stream>>>(A, Xa, Ya);
  k_ns<<<dim3(4,4,64), 256, 0, stream>>>(Xa, Ya, Xb, Yb);
  k_ns<<<dim3(4,4,64), 256, 0, stream>>>(Xb, Yb, Xa, Ya);
  k_ns<<<dim3(4,4,64), 256, 0, stream>>>(Xa, Ya, Xb, Yb);
  hipMemsetAsync(w, 0, (size_t)B_*NP*sizeof(float), stream);
  k_admm5<<<dim3(25*B_), 256, 0, stream>>>(Xb, p, w);
  k_finish<<<dim3(B_), 256, 0, stream>>>(w, v, mlg, mlb, mw, mb, outp);
}